// Round 13
// baseline (280.199 us; speedup 1.0000x reference)
//
#include <hip/hip_runtime.h>
#include <math.h>

// Problem constants
#define BN 256
#define TN 64
#define LN 32
#define DN 128
#define SN 4
#define HN 32   // column-panel width for the blocked elimination

#define LOG2PI 1.8378770664093453f

__device__ __forceinline__ float bcastf(float v, int lane) {
    return __builtin_bit_cast(float, __builtin_amdgcn_readlane(__builtin_bit_cast(int, v), lane));
}
// bf16-truncation pack of multipliers: 2 per VGPR, shift-only (R10/R11-proven)
__device__ __forceinline__ float bf_lo(unsigned m) { return __builtin_bit_cast(float, m << 16); }
__device__ __forceinline__ float bf_hi(unsigned m) { return __builtin_bit_cast(float, m & 0xFFFF0000u); }

// Intra-wave LDS ordering fence. The DS pipe is in-order per wave, but the
// COMPILER may reorder LDS reads across an exec-masked publish (R12 NaN).
// wave_barrier is the canonical scheduler pseudo-op; the asm clobber pins
// IR-level motion. Zero runtime cost.
__device__ __forceinline__ void wavefence() {
    __builtin_amdgcn_wave_barrier();
    asm volatile("" ::: "memory");
}

// ===========================================================================
// Lessons R1-R12:
//  * Per-lane array subscripts must be frontend-time constants (templates).
//  * Min-occupancy mandates -> scratch storm (R9). asm/f32x2 -> +36 VGPR (R10).
//  * v_readlane ~8 cyc: the ~2100 sweep readlanes ARE the kernel (R7/8/11).
//  * R12: masked-publish + same-wave broadcast read is VALUE-correct but
//    needs explicit compiler ordering fences (this round's fix).
// ===========================================================================

// LDS plane layout: [32 rows][8 chunks][4 dwords]; chunk q of row i at
// position (q + i + (i>>3)) & 7 -> conflict-free b128 fills & staging stores.
__device__ __forceinline__ int chunk_pos(int q, int i) { return (q + i + (i >> 3)) & 7; }

// ---- shared template helpers ---------------------------------------------
template<int Q>
__device__ __forceinline__ void fillp(float (&r)[HN], const float* plane, int slot) {
    if constexpr (Q < 8) {
        const float4 v = *(const float4*)(plane + slot * 32 + chunk_pos(Q, slot) * 4);
        r[4 * Q + 0] = v.x; r[4 * Q + 1] = v.y;
        r[4 * Q + 2] = v.z; r[4 * Q + 3] = v.w;
        fillp<Q + 1>(r, plane, slot);
    }
}
// trace: tr += <kinv_row, r>; sm += <kinv_row, mu> with mu[j] from per-wave LDS
template<int JB, int J4>
__device__ __forceinline__ void trace_lds(const float (&r)[HN], const float* __restrict__ kp,
                                          const float* mudp, float& tr, float& sm) {
    if constexpr (J4 < 8) {
        float4 kv = *(const float4*)(kp + 4 * J4);
        float4 mv = *(const float4*)(mudp + JB + 4 * J4);
        tr = fmaf(kv.x, r[4 * J4 + 0], tr); sm = fmaf(kv.x, mv.x, sm);
        tr = fmaf(kv.y, r[4 * J4 + 1], tr); sm = fmaf(kv.y, mv.y, sm);
        tr = fmaf(kv.z, r[4 * J4 + 2], tr); sm = fmaf(kv.z, mv.z, sm);
        tr = fmaf(kv.w, r[4 * J4 + 3], tr); sm = fmaf(kv.w, mv.w, sm);
        trace_lds<JB, J4 + 1>(r, kp, mudp, tr, sm);
    }
}

// ---- publish machinery ----------------------------------------------------
// lane K writes its (exact-through-step-K) panel slice, chunks QS..7
template<int QS>
__device__ __forceinline__ void pub_write(const float (&r)[HN], float* pubp) {
    if constexpr (QS < 8) {
        *(float4*)(pubp + 4 * QS) = make_float4(r[4 * QS + 0], r[4 * QS + 1],
                                                r[4 * QS + 2], r[4 * QS + 3]);
        pub_write<QS + 1>(r, pubp);
    }
}
// r[chunks QS..7] -= c * pub[chunks QS..7]  (broadcast same-addr reads)
template<int QS>
__device__ __forceinline__ void row_fma(float (&r)[HN], float c, const float* pubp) {
    if constexpr (QS < 8) {
        float4 p = *(const float4*)(pubp + 4 * QS);
        r[4 * QS + 0] = fmaf(-c, p.x, r[4 * QS + 0]);
        r[4 * QS + 1] = fmaf(-c, p.y, r[4 * QS + 1]);
        r[4 * QS + 2] = fmaf(-c, p.z, r[4 * QS + 2]);
        r[4 * QS + 3] = fmaf(-c, p.w, r[4 * QS + 3]);
        row_fma<QS + 1>(r, c, pubp);
    }
}

// panel-1 pivots K=0..31: publish row K (lane K, fresh), d from published
// chunk, c = own r[K]/d (no cross-lane), full-width chunked update (cols<K
// self-zeroed -> dead, never published again).
template<int K>
__device__ __forceinline__ void p1_sweep(float (&r)[HN], unsigned (&m)[16],
                                         float& logdet, float* pubp, int lane) {
    if constexpr (K < HN) {
        constexpr int CK = K >> 2, CE = K & 3;
        if (lane == K) pub_write<CK>(r, pubp);
        wavefence();                     // publish visible before reads
        float4 pc = *(const float4*)(pubp + 4 * CK);
        float d = (CE == 0) ? pc.x : (CE == 1) ? pc.y : (CE == 2) ? pc.z : pc.w;
        logdet += __logf(d);
        float c = r[K] * __builtin_amdgcn_rcpf(d);
        r[4 * CK + 0] = fmaf(-c, pc.x, r[4 * CK + 0]);
        r[4 * CK + 1] = fmaf(-c, pc.y, r[4 * CK + 1]);
        r[4 * CK + 2] = fmaf(-c, pc.z, r[4 * CK + 2]);
        r[4 * CK + 3] = fmaf(-c, pc.w, r[4 * CK + 3]);
        row_fma<CK + 1>(r, c, pubp);
        wavefence();                     // reads done before next publish
        if constexpr (K & 1) m[K >> 1] |= (__builtin_bit_cast(unsigned, c) & 0xFFFF0000u);
        else                 m[K >> 1]  = (__builtin_bit_cast(unsigned, c) >> 16);
        p1_sweep<K + 1>(r, m, logdet, pubp, lane);
    }
}
// replay pivots 0..31 onto cols 32..63: lane K publishes its r2 (exact
// through step K-1; its own self-zeroing update comes after the publish).
template<int K>
__device__ __forceinline__ void p2_rep(float (&r)[HN], const unsigned (&m)[16],
                                       float* pubp, int lane) {
    if constexpr (K < HN) {
        if (lane == K) pub_write<0>(r, pubp);
        wavefence();
        float c = (K & 1) ? bf_hi(m[K >> 1]) : bf_lo(m[K >> 1]);
        row_fma<0>(r, c, pubp);
        wavefence();
        p2_rep<K + 1>(r, m, pubp, lane);
    }
}
// pivots 32..63 on trailing 32x32: publisher = lane 32+Q, d at local col Q.
template<int Q>
__device__ __forceinline__ void p2_solo(float (&r)[HN], float& logdet,
                                        float* pubp, int lane) {
    if constexpr (Q < HN) {
        constexpr int CQ = Q >> 2, CE = Q & 3;
        if (lane == 32 + Q) pub_write<CQ>(r, pubp);
        wavefence();
        float4 pc = *(const float4*)(pubp + 4 * CQ);
        float d = (CE == 0) ? pc.x : (CE == 1) ? pc.y : (CE == 2) ? pc.z : pc.w;
        logdet += __logf(d);
        float c = r[Q] * __builtin_amdgcn_rcpf(d);
        r[4 * CQ + 0] = fmaf(-c, pc.x, r[4 * CQ + 0]);
        r[4 * CQ + 1] = fmaf(-c, pc.y, r[4 * CQ + 1]);
        r[4 * CQ + 2] = fmaf(-c, pc.z, r[4 * CQ + 2]);
        r[4 * CQ + 3] = fmaf(-c, pc.w, r[4 * CQ + 3]);
        row_fma<CQ + 1>(r, c, pubp);
        wavefence();
        p2_solo<Q + 1>(r, logdet, pubp, lane);
    }
}

// ---------------------------------------------------------------------------
// k_chol: block = 256 threads = 4 waves = one (b, l-quad).
// LDS: 16KB staged panels + 512B pivot-row scratch + 1KB mu vectors = 17.9KB.
// Sweeps have ZERO readlanes; DS broadcast reads carry the pivot rows.
// ---------------------------------------------------------------------------
__global__ __launch_bounds__(256)
void k_chol(const float* __restrict__ Sg,
            const float* __restrict__ mus,
            const float* __restrict__ kinv,
            const float* __restrict__ logdetK,
            float* __restrict__ out) {
    __shared__ float st[4 * 1024];       // staged panels (16 KB)
    __shared__ float pubs[4 * 32];       // per-wave pivot-row scratch
    __shared__ float muds[4 * 64];       // per-wave mu vector

    int hw = blockIdx.x;                 // 2048 blocks
    int g = (hw & 7) * 256 + (hw >> 3);  // XCD x owns b in [x*32, x*32+32)
    int b = g >> 3, lg = g & 7;          // lg = l-quad 0..7

    int tid = threadIdx.x;
    int w = tid >> 6, lane = tid & 63;   // wave w <-> l = lg*4 + w; lane = row
    int l = lg * 4 + w;
    int slot = lane & 31;                // row within the staged half

    float mu = mus[((size_t)b * TN + lane) * LN + l];
    muds[w * 64 + lane] = mu;            // covered by the staging barriers below
    const float* kp = kinv + l * (TN * TN) + lane * TN;
    const float* plane = &st[w * 1024];
    float* pubp = &pubs[w * 32];
    const float* mudp = &muds[w * 64];

    // stage a 32-row x 32-col half-panel (rows r0..r0+31, cols c0..c0+31)
    auto stage = [&](int r0, int c0) {
#pragma unroll
        for (int it = 0; it < 4; ++it) {
            int m_ = tid + it * 256;     // 0..1023
            int j = m_ & 31, i = m_ >> 5;
            const float* gp = Sg + ((((size_t)b * TN + r0 + i) * TN + c0 + j) * LN + lg * 4);
            float4 v = *(const float4*)gp;
            int off = i * 32 + chunk_pos(j >> 2, i) * 4 + (j & 3);
            st[0 * 1024 + off] = v.x;
            st[1 * 1024 + off] = v.y;
            st[2 * 1024 + off] = v.z;
            st[3 * 1024 + off] = v.w;
        }
    };

    float tr = 0.0f, sm = 0.0f, logdet = 0.0f;
    unsigned m[16];
    float r1[HN];

    // ---- panel 1 (cols 0..31) ----
    stage(0, 0);
    __syncthreads();
    if (lane < 32) fillp<0>(r1, plane, slot);
    __syncthreads();
    stage(32, 0);
    __syncthreads();
    if (lane >= 32) fillp<0>(r1, plane, slot);

    trace_lds<0, 0>(r1, kp, mudp, tr, sm);
    p1_sweep<0>(r1, m, logdet, pubp, lane);   // mults -> m[16]; r1 dead

    // ---- panel 2 (cols 32..63) ----
    __syncthreads();                     // all waves done with panel-1 LDS
    float r2[HN];
    stage(0, 32);
    __syncthreads();
    if (lane < 32) fillp<0>(r2, plane, slot);
    __syncthreads();
    stage(32, 32);
    __syncthreads();
    if (lane >= 32) fillp<0>(r2, plane, slot);

    trace_lds<32, 0>(r2, kp + 32, mudp, tr, sm);
    p2_rep<0>(r2, m, pubp, lane);        // deferred right-half updates
    p2_solo<0>(r2, logdet, pubp, lane);  // trailing 32x32 pivots

    float contrib = tr + mu * sm;
#pragma unroll
    for (int off = 32; off >= 1; off >>= 1) contrib += __shfl_xor(contrib, off, 64);

    if (lane == 0) {
        float klp = 0.5f * (logdetK[l] - logdet - (float)TN + contrib);
        atomicAdd(&out[b], klp);
    }
}

// ======================== fused k_ll + k_kinv (R11, unchanged) =============
template<int J>
__device__ __forceinline__ void pan_load(float (&p)[HN], const float* __restrict__ Kmat,
                                         int i, int l, int jbase) {
    if constexpr (J < HN) {
        p[J] = Kmat[(i * TN + jbase + J) * LN + l];
        pan_load<J + 1>(p, Kmat, i, l, jbase);
    }
}
template<int K, int J>
__device__ __forceinline__ void ki_upd(float (&a)[HN], float c) {
    if constexpr (J < HN) {
        a[J] = fmaf(-c, bcastf(a[J], K), a[J]);
        ki_upd<K, J + 1>(a, c);
    }
}
template<int K>
__device__ __forceinline__ void ki_a1sweep(float (&a1)[HN], float& ld, float& piv, int i) {
    if constexpr (K < HN) {
        float dkk = bcastf(a1[K], K);
        ld += __logf(dkk);
        if (i == K) piv = dkk;
        float c = (i == K) ? 0.0f : a1[K] * __builtin_amdgcn_rcpf(dkk);
        ki_upd<K, K + 1>(a1, c);
        a1[K] = c;
        ki_a1sweep<K + 1>(a1, ld, piv, i);
    }
}
template<int K>
__device__ __forceinline__ void ki_replay(float (&a2)[HN], const float (&a1)[HN]) {
    if constexpr (K < HN) {
        ki_upd<K, 0>(a2, a1[K]);
        ki_replay<K + 1>(a2, a1);
    }
}
template<int Q, int J>
__device__ __forceinline__ void ki_upd2(float (&a2)[HN], float c) {
    if constexpr (J < HN) {
        a2[J] = fmaf(-c, bcastf(a2[J], 32 + Q), a2[J]);
        ki_upd2<Q, J + 1>(a2, c);
    }
}
template<int Q>
__device__ __forceinline__ void ki_a2sweep(float (&a2)[HN], float& ld, float& piv, int i) {
    if constexpr (Q < HN) {
        float dkk = bcastf(a2[Q], 32 + Q);
        ld += __logf(dkk);
        if (i == 32 + Q) piv = dkk;
        float c = (i == 32 + Q) ? 0.0f : a2[Q] * __builtin_amdgcn_rcpf(dkk);
        ki_upd2<Q, Q + 1>(a2, c);
        a2[Q] = c;
        ki_a2sweep<Q + 1>(a2, ld, piv, i);
    }
}
template<int J>
__device__ __forceinline__ void g1_init(float (&g)[HN], int i) {
    if constexpr (J < HN) { g[J] = (J == i) ? 1.0f : 0.0f; g1_init<J + 1>(g, i); }
}
template<int K, int J>
__device__ __forceinline__ void g1_updA(float (&g)[HN], float c) {
    if constexpr (J <= K) {
        g[J] = fmaf(-c, bcastf(g[J], K), g[J]);
        g1_updA<K, J + 1>(g, c);
    }
}
template<int K>
__device__ __forceinline__ void g1_phase1(float (&g)[HN], const float (&a1)[HN]) {
    if constexpr (K < HN) {
        g1_updA<K, 0>(g, a1[K]);
        g1_phase1<K + 1>(g, a1);
    }
}
template<int Q, int J>
__device__ __forceinline__ void g1_updB(float (&g)[HN], float c) {
    if constexpr (J < HN) {
        g[J] = fmaf(-c, bcastf(g[J], 32 + Q), g[J]);
        g1_updB<Q, J + 1>(g, c);
    }
}
template<int Q>
__device__ __forceinline__ void g1_phase2(float (&g)[HN], const float (&a2)[HN]) {
    if constexpr (Q < HN) {
        g1_updB<Q, 0>(g, a2[Q]);
        g1_phase2<Q + 1>(g, a2);
    }
}
template<int J>
__device__ __forceinline__ void g2_init(float (&g)[HN], int i) {
    if constexpr (J < HN) { g[J] = (32 + J == i) ? 1.0f : 0.0f; g2_init<J + 1>(g, i); }
}
template<int Q, int J>
__device__ __forceinline__ void g2_upd(float (&g)[HN], float c) {
    if constexpr (J <= Q) {
        g[J] = fmaf(-c, bcastf(g[J], 32 + Q), g[J]);
        g2_upd<Q, J + 1>(g, c);
    }
}
template<int Q>
__device__ __forceinline__ void g2_phase(float (&g)[HN], const float (&a2)[HN]) {
    if constexpr (Q < HN) {
        g2_upd<Q, 0>(g, a2[Q]);
        g2_phase<Q + 1>(g, a2);
    }
}
template<int J>
__device__ __forceinline__ void pan_out(const float (&g)[HN], float rdi,
                                        float* __restrict__ dst) {
    if constexpr (J < HN) {
        dst[J] = g[J] * rdi;
        pan_out<J + 1>(g, rdi, dst);
    }
}

__global__ __launch_bounds__(256)
void k_ll_kinv(const float* __restrict__ X,
               const float* __restrict__ Mn,
               const float* __restrict__ R,
               const float* __restrict__ Kmat,
               float* __restrict__ kinv,
               float* __restrict__ logdetK,
               float* __restrict__ out) {
    if (blockIdx.x < 64) {
        // 2 blocks per latent: both redo the sweeps, split the reconstruction
        if (threadIdx.x >= 64) return;
        const int l = blockIdx.x >> 1;
        const int half = blockIdx.x & 1;
        const int i = threadIdx.x;       // row

        float ld = 0.0f, piv = 1.0f;
        float a1[HN], a2[HN];
        pan_load<0>(a1, Kmat, i, l, 0);
        ki_a1sweep<0>(a1, ld, piv, i);
        pan_load<0>(a2, Kmat, i, l, 32);
        ki_replay<0>(a2, a1);
        ki_a2sweep<0>(a2, ld, piv, i);
        float rdi = __builtin_amdgcn_rcpf(piv);
        if (half == 0) {
            float g1[HN];
            g1_init<0>(g1, i);
            g1_phase1<0>(g1, a1);
            g1_phase2<0>(g1, a2);
            pan_out<0>(g1, rdi, kinv + l * (TN * TN) + i * TN);
        } else {
            float g2[HN];
            g2_init<0>(g2, i);
            g2_phase<0>(g2, a2);
            pan_out<0>(g2, rdi, kinv + l * (TN * TN) + i * TN + 32);
            if (i == 0) logdetK[l] = ld;
        }
        return;
    }

    // ---- log-likelihood block (b,s) ----
    int hw = blockIdx.x - 64;            // 1024 blocks
    int g = (hw & 7) * 128 + (hw >> 3);
    int b = g >> 2, s = g & 3;
    int tid = threadIdx.x;

    const float4* xp = (const float4*)(X + (size_t)b * TN * DN);
    const float4* mp = (const float4*)(Mn + ((size_t)(b * SN + s) * TN) * DN);

    int c = tid & 31;
    float4 rv = ((const float4*)R)[c];
    float4 ri = make_float4(1.0f / rv.x, 1.0f / rv.y, 1.0f / rv.z, 1.0f / rv.w);

    float acc = 0.0f;
#pragma unroll
    for (int it = 0; it < (TN * DN / 4) / 256; ++it) {
        int f = tid + it * 256;
        float4 xv = xp[f];
        float4 mv = mp[f];
        float dx = xv.x - mv.x; acc = fmaf(dx * dx, ri.x, acc);
        float dy = xv.y - mv.y; acc = fmaf(dy * dy, ri.y, acc);
        float dz = xv.z - mv.z; acc = fmaf(dz * dz, ri.z, acc);
        float dw = xv.w - mv.w; acc = fmaf(dw * dw, ri.w, acc);
    }
#pragma unroll
    for (int off = 32; off >= 1; off >>= 1) acc += __shfl_xor(acc, off, 64);

    __shared__ float wsum[4];
    if ((tid & 63) == 0) wsum[tid >> 6] = acc;
    __syncthreads();
    if (tid == 0) {
        float q = wsum[0] + wsum[1] + wsum[2] + wsum[3];
        float val = q * (0.5f / SN);
        if (s == 0) {
            float slr = 0.0f;
#pragma unroll
            for (int d = 0; d < DN; ++d) slr += __logf(R[d]);
            val += 0.5f * (float)TN * (slr + (float)DN * LOG2PI);
        }
        atomicAdd(&out[b], val);
    }
}

// ---------------------------------------------------------------------------
extern "C" void kernel_launch(void* const* d_in, const int* in_sizes, int n_in,
                              void* d_out, int out_size, void* d_ws, size_t ws_size,
                              hipStream_t stream) {
    const float* X   = (const float*)d_in[0];  // [B,T,D]
    const float* Mn  = (const float*)d_in[1];  // [B,S,T,D]
    const float* R   = (const float*)d_in[2];  // [D]
    const float* mus = (const float*)d_in[3];  // [B,T,L]
    const float* Sg  = (const float*)d_in[4];  // [B,T,T,L]
    const float* Km  = (const float*)d_in[5];  // [T,T,L]
    float* out = (float*)d_out;                // [B] fp32

    float* kinv = (float*)d_ws;                // 32*4096 floats = 512 KB
    float* ldK  = kinv + LN * TN * TN;         // 32 floats

    hipMemsetAsync(d_out, 0, BN * sizeof(float), stream);
    k_ll_kinv<<<64 + BN * SN, 256, 0, stream>>>(X, Mn, R, Km, kinv, ldK, out);
    k_chol<<<BN * 8, 256, 0, stream>>>(Sg, mus, kinv, ldK, out);
}

// Round 14
// 201.121 us; speedup vs baseline: 1.3932x; 1.3932x over previous
//
#include <hip/hip_runtime.h>
#include <math.h>

// Problem constants
#define BN 256
#define TN 64
#define LN 32
#define DN 128
#define SN 4
#define HN 32   // column-panel width for the blocked elimination

#define LOG2PI 1.8378770664093453f

__device__ __forceinline__ float bcastf(float v, int lane) {
    return __builtin_bit_cast(float, __builtin_amdgcn_readlane(__builtin_bit_cast(int, v), lane));
}

// ===========================================================================
// Lessons R1-R13:
//  * Register-array subscripts must be compile-time constants; min-occupancy
//    attrs -> scratch storm (R9); f32x2/asm -> VGPR bloat (R10); per-step
//    LDS publish -> latency-serial (R13).
//  * KEY (R7/R8/R11): perf scales INVERSELY with occupancy and per-wave
//    busy-cycles are constant -> the fully-unrolled ~55KB body thrashes the
//    32KB I$; every wave streams the whole kernel. THIS round: loops with a
//    fused-shift update (r[s-1] = f(r[s])) keep register indices constant
//    while cutting code to ~3KB. Multipliers -> bf16 LDS c-panel (numerics
//    proven R10/R11). Staging = R11's proven 16KB half-panels.
// ===========================================================================

// LDS plane layout: [32 rows][8 chunks][4 dwords]; chunk q of row i at
// position (q + i + (i>>3)) & 7 -> conflict-free b128 fills & staging stores.
__device__ __forceinline__ int chunk_pos(int q, int i) { return (q + i + (i >> 3)) & 7; }

// ---- shared template helpers (R11-proven) --------------------------------
template<int Q>
__device__ __forceinline__ void fillp(float (&r)[HN], const float* plane, int slot) {
    if constexpr (Q < 8) {
        const float4 v = *(const float4*)(plane + slot * 32 + chunk_pos(Q, slot) * 4);
        r[4 * Q + 0] = v.x; r[4 * Q + 1] = v.y;
        r[4 * Q + 2] = v.z; r[4 * Q + 3] = v.w;
        fillp<Q + 1>(r, plane, slot);
    }
}
template<int JBASE, int J4>
__device__ __forceinline__ void trace_half(const float (&r)[HN], const float* __restrict__ kp,
                                           float mu, float& tr, float& sm) {
    if constexpr (J4 < 8) {
        float4 kv = *(const float4*)(kp + 4 * J4);
        tr = fmaf(kv.x, r[4 * J4 + 0], tr); sm = fmaf(kv.x, bcastf(mu, JBASE + 4 * J4 + 0), sm);
        tr = fmaf(kv.y, r[4 * J4 + 1], tr); sm = fmaf(kv.y, bcastf(mu, JBASE + 4 * J4 + 1), sm);
        tr = fmaf(kv.z, r[4 * J4 + 2], tr); sm = fmaf(kv.z, bcastf(mu, JBASE + 4 * J4 + 2), sm);
        tr = fmaf(kv.w, r[4 * J4 + 3], tr); sm = fmaf(kv.w, bcastf(mu, JBASE + 4 * J4 + 3), sm);
        trace_half<JBASE, J4 + 1>(r, kp, mu, tr, sm);
    }
}

// ---------------------------------------------------------------------------
// k_chol: block = 256 threads = 4 waves = one (b, l-quad).
// LOOPED sweeps (small code, I$-resident):
//  * c1 (K=0..31): d, c from slot 0; fused-shift update writes r[s-1]=f(r[s])
//    (col K retires, live window stays at slot 0). Garbage sources only ever
//    write garbage slots (live targets s-1<=30-K come from live sources
//    s<=31-K). Multiplier c -> bf16 LDS c-panel (lane-rotated index).
//  * rep (K=0..31): c from c-panel; full-width, no shift (R8 algebra).
//  * solo (Q=0..31): same as c1 with publisher lane 32+Q.
// LDS: 16KB half-panel staging + 16KB bf16 c-panel = 32KB -> 5 blocks/CU.
// ---------------------------------------------------------------------------
__global__ __launch_bounds__(256)
void k_chol(const float* __restrict__ Sg,
            const float* __restrict__ mus,
            const float* __restrict__ kinv,
            const float* __restrict__ logdetK,
            float* __restrict__ out) {
    __shared__ float st[4 * 1024];             // 16 KB staging
    __shared__ unsigned short cp16[4 * 2048];  // 16 KB bf16 c-panel

    int hw = blockIdx.x;                 // 2048 blocks
    int g = (hw & 7) * 256 + (hw >> 3);  // XCD x owns b in [x*32, x*32+32)
    int b = g >> 3, lg = g & 7;          // lg = l-quad 0..7

    int tid = threadIdx.x;
    int w = tid >> 6, lane = tid & 63;   // wave w <-> l = lg*4 + w; lane = row
    int l = lg * 4 + w;
    int slot = lane & 31;                // row within the staged half

    float mu = mus[((size_t)b * TN + lane) * LN + l];
    const float* kp = kinv + l * (TN * TN) + lane * TN;
    const float* plane = &st[w * 1024];
    unsigned short* cpp = &cp16[w * 2048 + lane * 32];

    // stage a 32-row x 32-col half-panel (rows r0..r0+31, cols c0..c0+31)
    auto stage = [&](int r0, int c0) {
#pragma unroll
        for (int it = 0; it < 4; ++it) {
            int m_ = tid + it * 256;     // 0..1023
            int j = m_ & 31, i = m_ >> 5;
            const float* gp = Sg + ((((size_t)b * TN + r0 + i) * TN + c0 + j) * LN + lg * 4);
            float4 v = *(const float4*)gp;
            int off = i * 32 + chunk_pos(j >> 2, i) * 4 + (j & 3);
            st[0 * 1024 + off] = v.x;
            st[1 * 1024 + off] = v.y;
            st[2 * 1024 + off] = v.z;
            st[3 * 1024 + off] = v.w;
        }
    };

    float tr = 0.0f, sm = 0.0f, logdet = 0.0f;
    float r1[HN];

    // ---- panel 1 (cols 0..31) ----
    stage(0, 0);
    __syncthreads();
    if (lane < 32) fillp<0>(r1, plane, slot);
    __syncthreads();
    stage(32, 0);
    __syncthreads();
    if (lane >= 32) fillp<0>(r1, plane, slot);

    trace_half<0, 0>(r1, kp, mu, tr, sm);

    // c1 sweep: pivots 0..31, fused shift, mult -> bf16 LDS
#pragma unroll 2
    for (int K = 0; K < HN; ++K) {
        float d = bcastf(r1[0], K);
        logdet += __logf(d);
        float c = r1[0] * __builtin_amdgcn_rcpf(d);
        cpp[(K + lane) & 31] = (unsigned short)(__builtin_bit_cast(unsigned, c) >> 16);
#pragma unroll
        for (int s = 1; s < HN; ++s)
            r1[s - 1] = fmaf(-c, bcastf(r1[s], K), r1[s]);
    }

    // ---- panel 2 (cols 32..63) ----
    __syncthreads();                     // all waves done with panel-1 LDS
    float r2[HN];
    stage(0, 32);
    __syncthreads();
    if (lane < 32) fillp<0>(r2, plane, slot);
    __syncthreads();
    stage(32, 32);
    __syncthreads();
    if (lane >= 32) fillp<0>(r2, plane, slot);

    trace_half<32, 0>(r2, kp + 32, mu, tr, sm);

    // replay pivots 0..31 onto cols 32..63 (R8 algebra; c from bf16 c-panel)
#pragma unroll 4
    for (int K = 0; K < HN; ++K) {
        float c = __builtin_bit_cast(float, (unsigned)cpp[(K + lane) & 31] << 16);
#pragma unroll
        for (int s = 0; s < HN; ++s)
            r2[s] = fmaf(-c, bcastf(r2[s], K), r2[s]);
    }

    // solo pivots 32..63 on trailing 32x32 (publisher lane 32+Q), fused shift
#pragma unroll 2
    for (int Q = 0; Q < HN; ++Q) {
        float d = bcastf(r2[0], 32 + Q);
        logdet += __logf(d);
        float c = r2[0] * __builtin_amdgcn_rcpf(d);
#pragma unroll
        for (int s = 1; s < HN; ++s)
            r2[s - 1] = fmaf(-c, bcastf(r2[s], 32 + Q), r2[s]);
    }

    float contrib = tr + mu * sm;
#pragma unroll
    for (int off = 32; off >= 1; off >>= 1) contrib += __shfl_xor(contrib, off, 64);

    if (lane == 0) {
        float klp = 0.5f * (logdetK[l] - logdet - (float)TN + contrib);
        atomicAdd(&out[b], klp);
    }
}

// ======================== fused k_ll + k_kinv (R11, unchanged) =============
template<int J>
__device__ __forceinline__ void pan_load(float (&p)[HN], const float* __restrict__ Kmat,
                                         int i, int l, int jbase) {
    if constexpr (J < HN) {
        p[J] = Kmat[(i * TN + jbase + J) * LN + l];
        pan_load<J + 1>(p, Kmat, i, l, jbase);
    }
}
template<int K, int J>
__device__ __forceinline__ void ki_upd(float (&a)[HN], float c) {
    if constexpr (J < HN) {
        a[J] = fmaf(-c, bcastf(a[J], K), a[J]);
        ki_upd<K, J + 1>(a, c);
    }
}
template<int K>
__device__ __forceinline__ void ki_a1sweep(float (&a1)[HN], float& ld, float& piv, int i) {
    if constexpr (K < HN) {
        float dkk = bcastf(a1[K], K);
        ld += __logf(dkk);
        if (i == K) piv = dkk;
        float c = (i == K) ? 0.0f : a1[K] * __builtin_amdgcn_rcpf(dkk);
        ki_upd<K, K + 1>(a1, c);
        a1[K] = c;
        ki_a1sweep<K + 1>(a1, ld, piv, i);
    }
}
template<int K>
__device__ __forceinline__ void ki_replay(float (&a2)[HN], const float (&a1)[HN]) {
    if constexpr (K < HN) {
        ki_upd<K, 0>(a2, a1[K]);
        ki_replay<K + 1>(a2, a1);
    }
}
template<int Q, int J>
__device__ __forceinline__ void ki_upd2(float (&a2)[HN], float c) {
    if constexpr (J < HN) {
        a2[J] = fmaf(-c, bcastf(a2[J], 32 + Q), a2[J]);
        ki_upd2<Q, J + 1>(a2, c);
    }
}
template<int Q>
__device__ __forceinline__ void ki_a2sweep(float (&a2)[HN], float& ld, float& piv, int i) {
    if constexpr (Q < HN) {
        float dkk = bcastf(a2[Q], 32 + Q);
        ld += __logf(dkk);
        if (i == 32 + Q) piv = dkk;
        float c = (i == 32 + Q) ? 0.0f : a2[Q] * __builtin_amdgcn_rcpf(dkk);
        ki_upd2<Q, Q + 1>(a2, c);
        a2[Q] = c;
        ki_a2sweep<Q + 1>(a2, ld, piv, i);
    }
}
template<int J>
__device__ __forceinline__ void g1_init(float (&g)[HN], int i) {
    if constexpr (J < HN) { g[J] = (J == i) ? 1.0f : 0.0f; g1_init<J + 1>(g, i); }
}
template<int K, int J>
__device__ __forceinline__ void g1_updA(float (&g)[HN], float c) {
    if constexpr (J <= K) {
        g[J] = fmaf(-c, bcastf(g[J], K), g[J]);
        g1_updA<K, J + 1>(g, c);
    }
}
template<int K>
__device__ __forceinline__ void g1_phase1(float (&g)[HN], const float (&a1)[HN]) {
    if constexpr (K < HN) {
        g1_updA<K, 0>(g, a1[K]);
        g1_phase1<K + 1>(g, a1);
    }
}
template<int Q, int J>
__device__ __forceinline__ void g1_updB(float (&g)[HN], float c) {
    if constexpr (J < HN) {
        g[J] = fmaf(-c, bcastf(g[J], 32 + Q), g[J]);
        g1_updB<Q, J + 1>(g, c);
    }
}
template<int Q>
__device__ __forceinline__ void g1_phase2(float (&g)[HN], const float (&a2)[HN]) {
    if constexpr (Q < HN) {
        g1_updB<Q, 0>(g, a2[Q]);
        g1_phase2<Q + 1>(g, a2);
    }
}
template<int J>
__device__ __forceinline__ void g2_init(float (&g)[HN], int i) {
    if constexpr (J < HN) { g[J] = (32 + J == i) ? 1.0f : 0.0f; g2_init<J + 1>(g, i); }
}
template<int Q, int J>
__device__ __forceinline__ void g2_upd(float (&g)[HN], float c) {
    if constexpr (J <= Q) {
        g[J] = fmaf(-c, bcastf(g[J], 32 + Q), g[J]);
        g2_upd<Q, J + 1>(g, c);
    }
}
template<int Q>
__device__ __forceinline__ void g2_phase(float (&g)[HN], const float (&a2)[HN]) {
    if constexpr (Q < HN) {
        g2_upd<Q, 0>(g, a2[Q]);
        g2_phase<Q + 1>(g, a2);
    }
}
template<int J>
__device__ __forceinline__ void pan_out(const float (&g)[HN], float rdi,
                                        float* __restrict__ dst) {
    if constexpr (J < HN) {
        dst[J] = g[J] * rdi;
        pan_out<J + 1>(g, rdi, dst);
    }
}

__global__ __launch_bounds__(256)
void k_ll_kinv(const float* __restrict__ X,
               const float* __restrict__ Mn,
               const float* __restrict__ R,
               const float* __restrict__ Kmat,
               float* __restrict__ kinv,
               float* __restrict__ logdetK,
               float* __restrict__ out) {
    if (blockIdx.x < 64) {
        // 2 blocks per latent: both redo the sweeps, split the reconstruction
        if (threadIdx.x >= 64) return;
        const int l = blockIdx.x >> 1;
        const int half = blockIdx.x & 1;
        const int i = threadIdx.x;       // row

        float ld = 0.0f, piv = 1.0f;
        float a1[HN], a2[HN];
        pan_load<0>(a1, Kmat, i, l, 0);
        ki_a1sweep<0>(a1, ld, piv, i);
        pan_load<0>(a2, Kmat, i, l, 32);
        ki_replay<0>(a2, a1);
        ki_a2sweep<0>(a2, ld, piv, i);
        float rdi = __builtin_amdgcn_rcpf(piv);
        if (half == 0) {
            float g1[HN];
            g1_init<0>(g1, i);
            g1_phase1<0>(g1, a1);
            g1_phase2<0>(g1, a2);
            pan_out<0>(g1, rdi, kinv + l * (TN * TN) + i * TN);
        } else {
            float g2[HN];
            g2_init<0>(g2, i);
            g2_phase<0>(g2, a2);
            pan_out<0>(g2, rdi, kinv + l * (TN * TN) + i * TN + 32);
            if (i == 0) logdetK[l] = ld;
        }
        return;
    }

    // ---- log-likelihood block (b,s) ----
    int hw = blockIdx.x - 64;            // 1024 blocks
    int g = (hw & 7) * 128 + (hw >> 3);
    int b = g >> 2, s = g & 3;
    int tid = threadIdx.x;

    const float4* xp = (const float4*)(X + (size_t)b * TN * DN);
    const float4* mp = (const float4*)(Mn + ((size_t)(b * SN + s) * TN) * DN);

    int c = tid & 31;
    float4 rv = ((const float4*)R)[c];
    float4 ri = make_float4(1.0f / rv.x, 1.0f / rv.y, 1.0f / rv.z, 1.0f / rv.w);

    float acc = 0.0f;
#pragma unroll
    for (int it = 0; it < (TN * DN / 4) / 256; ++it) {
        int f = tid + it * 256;
        float4 xv = xp[f];
        float4 mv = mp[f];
        float dx = xv.x - mv.x; acc = fmaf(dx * dx, ri.x, acc);
        float dy = xv.y - mv.y; acc = fmaf(dy * dy, ri.y, acc);
        float dz = xv.z - mv.z; acc = fmaf(dz * dz, ri.z, acc);
        float dw = xv.w - mv.w; acc = fmaf(dw * dw, ri.w, acc);
    }
#pragma unroll
    for (int off = 32; off >= 1; off >>= 1) acc += __shfl_xor(acc, off, 64);

    __shared__ float wsum[4];
    if ((tid & 63) == 0) wsum[tid >> 6] = acc;
    __syncthreads();
    if (tid == 0) {
        float q = wsum[0] + wsum[1] + wsum[2] + wsum[3];
        float val = q * (0.5f / SN);
        if (s == 0) {
            float slr = 0.0f;
#pragma unroll
            for (int d = 0; d < DN; ++d) slr += __logf(R[d]);
            val += 0.5f * (float)TN * (slr + (float)DN * LOG2PI);
        }
        atomicAdd(&out[b], val);
    }
}

// ---------------------------------------------------------------------------
extern "C" void kernel_launch(void* const* d_in, const int* in_sizes, int n_in,
                              void* d_out, int out_size, void* d_ws, size_t ws_size,
                              hipStream_t stream) {
    const float* X   = (const float*)d_in[0];  // [B,T,D]
    const float* Mn  = (const float*)d_in[1];  // [B,S,T,D]
    const float* R   = (const float*)d_in[2];  // [D]
    const float* mus = (const float*)d_in[3];  // [B,T,L]
    const float* Sg  = (const float*)d_in[4];  // [B,T,T,L]
    const float* Km  = (const float*)d_in[5];  // [T,T,L]
    float* out = (float*)d_out;                // [B] fp32

    float* kinv = (float*)d_ws;                // 32*4096 floats = 512 KB
    float* ldK  = kinv + LN * TN * TN;         // 32 floats

    hipMemsetAsync(d_out, 0, BN * sizeof(float), stream);
    k_ll_kinv<<<64 + BN * SN, 256, 0, stream>>>(X, Mn, R, Km, kinv, ldK, out);
    k_chol<<<BN * 8, 256, 0, stream>>>(Sg, mus, kinv, ldK, out);
}